// Round 2
// baseline (4326.082 us; speedup 1.0000x reference)
//
#include <hip/hip_runtime.h>

#define B_   128
#define S_   256
#define D_   512
#define L_   4
#define H_   8
#define DH_  64
#define FF_  512
#define M_   32768   // B_*S_
#define EPS_ 1e-3f

typedef unsigned short u16;
typedef unsigned int   u32;
typedef __bf16 bf16_8 __attribute__((ext_vector_type(8)));
typedef float  f32_4  __attribute__((ext_vector_type(4)));

__device__ __forceinline__ float bf2f(u16 u) {
  union { u32 i; float f; } x; x.i = ((u32)u) << 16; return x.f;
}
__device__ __forceinline__ u16 f2bf(float f) {
  union { float f; u32 i; } x; x.f = f;
  u32 r = x.i + 0x7fffu + ((x.i >> 16) & 1u);
  return (u16)(r >> 16);
}
__device__ __forceinline__ void unpack2(u32 u, float& a, float& b) {
  union { u32 i; float f; } lo, hi;
  lo.i = u << 16; hi.i = u & 0xffff0000u;
  a = lo.f; b = hi.f;
}
__device__ __forceinline__ float dot8(uint4 a, uint4 b) {
  u32 au[4] = {a.x, a.y, a.z, a.w};
  u32 bu[4] = {b.x, b.y, b.z, b.w};
  float s = 0.f;
#pragma unroll
  for (int i = 0; i < 4; i++) {
    float a0, a1, b0, b1;
    unpack2(au[i], a0, a1);
    unpack2(bu[i], b0, b1);
    s = fmaf(a0, b0, s);
    s = fmaf(a1, b1, s);
  }
  return s;
}

// ---------------- embedding: h_bf16 = bf16(embed[seq] + pos), f32 inputs ----------------
__global__ __launch_bounds__(256) void k_embed(const int* __restrict__ seq,
    const float* __restrict__ pos, const float* __restrict__ emb,
    u16* __restrict__ h)
{
  int t = blockIdx.x * 256 + threadIdx.x;   // M_*64 threads, 8 elems each
  int row = t >> 6;
  int c = (t & 63) * 8;
  int s = row & (S_ - 1);
  int tok = seq[row];
  const float* ep = emb + (size_t)tok * D_ + c;
  const float* pp = pos + (size_t)s * D_ + c;
  float4 e0 = *(const float4*)ep;
  float4 e1 = *(const float4*)(ep + 4);
  float4 p0 = *(const float4*)pp;
  float4 p1 = *(const float4*)(pp + 4);
  u32 o[4];
  o[0] = (u32)f2bf(e0.x + p0.x) | ((u32)f2bf(e0.y + p0.y) << 16);
  o[1] = (u32)f2bf(e0.z + p0.z) | ((u32)f2bf(e0.w + p0.w) << 16);
  o[2] = (u32)f2bf(e1.x + p1.x) | ((u32)f2bf(e1.y + p1.y) << 16);
  o[3] = (u32)f2bf(e1.z + p1.z) | ((u32)f2bf(e1.w + p1.w) << 16);
  *(uint4*)&h[(size_t)row * D_ + c] = make_uint4(o[0], o[1], o[2], o[3]);
}

// ------- transpose all 24 [512x512] f32 weights -> bf16 Wt[n][k] -------
__global__ __launch_bounds__(256) void k_transpose(
    const float* __restrict__ Wq, const float* __restrict__ Wk, const float* __restrict__ Wv,
    const float* __restrict__ Wo, const float* __restrict__ W1, const float* __restrict__ W2,
    u16* __restrict__ Wt)
{
  __shared__ u16 tile[32][33];
  int mat = blockIdx.z;           // 0..23
  int layer = mat / 6, w = mat % 6;
  const float* src = (w == 0) ? Wq : (w == 1) ? Wk : (w == 2) ? Wv
                   : (w == 3) ? Wo : (w == 4) ? W1 : W2;
  src += (size_t)layer * (D_ * D_);
  u16* dst = Wt + (size_t)mat * (D_ * D_);
  int bx = blockIdx.x * 32;   // n
  int by = blockIdx.y * 32;   // k
  int tx = threadIdx.x & 31, ty = threadIdx.x >> 5;
#pragma unroll
  for (int i = 0; i < 32; i += 8)
    tile[ty + i][tx] = f2bf(src[(size_t)(by + ty + i) * D_ + bx + tx]);
  __syncthreads();
#pragma unroll
  for (int i = 0; i < 32; i += 8)
    dst[(size_t)(bx + ty + i) * D_ + by + tx] = tile[tx][ty + i];
}

// ---------------- GEMM: C[M,512] = A[M,512](bf16) x Bt[n][k](bf16) + bias(f32) ----------------
// mode 0: outb bf16 = A*B + bias
// mode 1: outb bf16 = relu(A*B + bias)
// mode 2: outf f32  = A*B + bias + resid(bf16)     (pre-BN buffer)
__global__ __launch_bounds__(256) void k_gemm(
    const u16* __restrict__ A, const u16* __restrict__ Bt,
    const float* __restrict__ bias, const u16* __restrict__ resid,
    u16* __restrict__ outb, float* __restrict__ outf, int mode)
{
  __shared__ u16 As[128][40];
  __shared__ u16 Bs[128][40];
  int tid = threadIdx.x;
  int m0 = blockIdx.x * 128;
  int n0 = blockIdx.y * 128;
  int wid = tid >> 6, lane = tid & 63;
  int wm = (wid >> 1) * 64, wn = (wid & 1) * 64;
  f32_4 acc[4][4] = {};
  int srow = tid >> 1;
  int scol = (tid & 1) * 16;
  const u16* Ap = A  + (size_t)(m0 + srow) * 512 + scol;
  const u16* Bp = Bt + (size_t)(n0 + srow) * 512 + scol;
  int fr = lane & 15;
  int fk = (lane >> 4) * 8;

  for (int k0 = 0; k0 < 512; k0 += 32) {
    uint4 a0 = *(const uint4*)(Ap + k0);
    uint4 a1 = *(const uint4*)(Ap + k0 + 8);
    uint4 b0 = *(const uint4*)(Bp + k0);
    uint4 b1 = *(const uint4*)(Bp + k0 + 8);
    __syncthreads();
    *(uint4*)&As[srow][scol]     = a0;
    *(uint4*)&As[srow][scol + 8] = a1;
    *(uint4*)&Bs[srow][scol]     = b0;
    *(uint4*)&Bs[srow][scol + 8] = b1;
    __syncthreads();
    bf16_8 afr[4], bfr[4];
#pragma unroll
    for (int i = 0; i < 4; i++) {
      afr[i] = *(const bf16_8*)&As[wm + i * 16 + fr][fk];
      bfr[i] = *(const bf16_8*)&Bs[wn + i * 16 + fr][fk];
    }
#pragma unroll
    for (int i = 0; i < 4; i++)
#pragma unroll
      for (int j = 0; j < 4; j++)
        acc[i][j] = __builtin_amdgcn_mfma_f32_16x16x32_bf16(afr[i], bfr[j], acc[i][j], 0, 0, 0);
  }

  int rbase = (lane >> 4) * 4;
#pragma unroll
  for (int j = 0; j < 4; j++) {
    int col = n0 + wn + j * 16 + fr;
    float bv = bias[col];
#pragma unroll
    for (int i = 0; i < 4; i++) {
      int row = m0 + wm + i * 16 + rbase;
#pragma unroll
      for (int r = 0; r < 4; r++) {
        float c = acc[i][j][r] + bv;
        if (mode == 1) c = fmaxf(c, 0.f);
        size_t idx = (size_t)(row + r) * 512 + col;
        if (mode == 2) {
          c += bf2f(resid[idx]);
          outf[idx] = c;
        } else {
          outb[idx] = f2bf(c);
        }
      }
    }
  }
}

// ---------------- attention: one block per (b,h), one thread per query (bf16 in/out) ----------------
__global__ __launch_bounds__(256) void k_attn(
    const u16* __restrict__ q, const u16* __restrict__ k,
    const u16* __restrict__ v, u16* __restrict__ attn)
{
  __shared__ u16 Ks[256][64];
  __shared__ u16 Vs[256][64];
  int tid = threadIdx.x;
  int bh = blockIdx.x;
  int b = bh >> 3, h = bh & 7;
  size_t base = ((size_t)b * S_) * D_ + (size_t)h * DH_;
#pragma unroll
  for (int r = 0; r < 8; r++) {
    int row = r * 32 + (tid >> 3);
    int c = (tid & 7) * 8;
    size_t g = base + (size_t)row * D_ + c;
    *(uint4*)&Ks[row][c] = *(const uint4*)&k[g];
    *(uint4*)&Vs[row][c] = *(const uint4*)&v[g];
  }
  uint4 qreg[8];
  {
    size_t g = base + (size_t)tid * D_;
#pragma unroll
    for (int c = 0; c < 8; c++) qreg[c] = *(const uint4*)&q[g + c * 8];
  }
  __syncthreads();

  // pass 1: running max + sum of exp
  float mval = -1e30f, lval = 0.f;
  for (int j = 0; j < 256; j++) {
    float s = 0.f;
#pragma unroll
    for (int c = 0; c < 8; c++)
      s += dot8(qreg[c], *(const uint4*)&Ks[j][c * 8]);
    s *= 0.125f;
    float mn = fmaxf(mval, s);
    lval = lval * __expf(mval - mn) + __expf(s - mn);
    mval = mn;
  }
  // pass 2: P*V
  float accv[64];
#pragma unroll
  for (int i = 0; i < 64; i++) accv[i] = 0.f;
  for (int j = 0; j < 256; j++) {
    float s = 0.f;
#pragma unroll
    for (int c = 0; c < 8; c++)
      s += dot8(qreg[c], *(const uint4*)&Ks[j][c * 8]);
    float p = __expf(s * 0.125f - mval);
#pragma unroll
    for (int c = 0; c < 8; c++) {
      uint4 vv = *(const uint4*)&Vs[j][c * 8];
      u32 vu[4] = {vv.x, vv.y, vv.z, vv.w};
#pragma unroll
      for (int i = 0; i < 4; i++) {
        float v0, v1;
        unpack2(vu[i], v0, v1);
        accv[c * 8 + i * 2]     = fmaf(p, v0, accv[c * 8 + i * 2]);
        accv[c * 8 + i * 2 + 1] = fmaf(p, v1, accv[c * 8 + i * 2 + 1]);
      }
    }
  }
  float linv = 1.f / lval;
  size_t g = base + (size_t)tid * D_;
#pragma unroll
  for (int c = 0; c < 8; c++) {
    u32 o[4];
#pragma unroll
    for (int i = 0; i < 4; i++) {
      o[i] = (u32)f2bf(accv[c * 8 + i * 2] * linv)
           | ((u32)f2bf(accv[c * 8 + i * 2 + 1] * linv) << 16);
    }
    *(uint4*)&attn[g + c * 8] = make_uint4(o[0], o[1], o[2], o[3]);
  }
}

// ---------------- batchnorm ----------------
__global__ __launch_bounds__(256) void k_zero(float* p, int n) {
  int t = blockIdx.x * 256 + threadIdx.x;
  if (t < n) p[t] = 0.f;
}

__global__ __launch_bounds__(256) void k_bnstats(const float* __restrict__ P,
                                                 float* __restrict__ stats) {
  int tid = threadIdx.x;
  size_t row0 = (size_t)blockIdx.x * 64;
  float s0 = 0, q0 = 0, s1 = 0, q1 = 0;
  for (int r = 0; r < 64; r++) {
    const float* p = P + (row0 + r) * 512;
    float a = p[tid], b = p[tid + 256];
    s0 += a; q0 = fmaf(a, a, q0);
    s1 += b; q1 = fmaf(b, b, q1);
  }
  atomicAdd(&stats[tid], s0);
  atomicAdd(&stats[tid + 256], s1);
  atomicAdd(&stats[512 + tid], q0);
  atomicAdd(&stats[512 + tid + 256], q1);
}

// writes bf16 (outb) when outf==nullptr, else f32 to outf (final layer -> d_out)
__global__ __launch_bounds__(256) void k_bnapply(const float* __restrict__ P,
    const float* __restrict__ stats, const float* __restrict__ gamma,
    const float* __restrict__ beta, u16* __restrict__ outb, float* __restrict__ outf)
{
  size_t t = (size_t)blockIdx.x * 256 + threadIdx.x;
  int f = (int)(t & 511);
  const float inv = 1.f / 32768.f;
  float mu = stats[f] * inv;
  float var = stats[512 + f] * inv - mu * mu;
  float sc = gamma[f] * rsqrtf(var + EPS_);
  float sh = beta[f] - mu * sc;
  float val = P[t] * sc + sh;
  if (outf) outf[t] = val;
  else      outb[t] = f2bf(val);
}

// ---------------- launch ----------------
extern "C" void kernel_launch(void* const* d_in, const int* in_sizes, int n_in,
                              void* d_out, int out_size, void* d_ws, size_t ws_size,
                              hipStream_t stream)
{
  const int*   seq = (const int*)d_in[0];
  const float* pos = (const float*)d_in[1];
  const float* emb = (const float*)d_in[2];
  const float* Wq  = (const float*)d_in[3];
  const float* bq  = (const float*)d_in[4];
  const float* Wk  = (const float*)d_in[5];
  const float* bk  = (const float*)d_in[6];
  const float* Wv  = (const float*)d_in[7];
  const float* bv  = (const float*)d_in[8];
  const float* Wo  = (const float*)d_in[9];
  const float* bo  = (const float*)d_in[10];
  const float* g1  = (const float*)d_in[11];
  const float* be1 = (const float*)d_in[12];
  const float* W1  = (const float*)d_in[13];
  const float* b1  = (const float*)d_in[14];
  const float* W2  = (const float*)d_in[15];
  const float* b2  = (const float*)d_in[16];
  const float* g2  = (const float*)d_in[17];
  const float* be2 = (const float*)d_in[18];

  char* ws = (char*)d_ws;
  const size_t SZH = (size_t)M_ * D_ * 2;        // 32 MiB per bf16 activation
  u16* hb16 = (u16*)(ws);                        // master activation (bf16)
  u16* qB   = (u16*)(ws + SZH);
  u16* kB   = (u16*)(ws + 2 * SZH);
  u16* vB   = (u16*)(ws + 3 * SZH);
  u16* aB   = (u16*)(ws + 4 * SZH);
  float* PB = (float*)(ws + 2 * SZH);            // f32 pre-BN, overlays kB,vB (dead then)
  u16* tB   = qB;                                // FFN hidden reuses q
  u16* Wt   = (u16*)(ws + 5 * SZH);
  float* stats = (float*)(ws + 5 * SZH + (size_t)24 * D_ * D_ * 2);

  dim3 blk(256);
  k_zero<<<32, blk, 0, stream>>>(stats, 8192);
  k_transpose<<<dim3(16, 16, 24), blk, 0, stream>>>(Wq, Wk, Wv, Wo, W1, W2, Wt);
  k_embed<<<M_ * 64 / 256, blk, 0, stream>>>(seq, pos, emb, hb16);

  dim3 ggrid(M_ / 128, 512 / 128);
  for (int l = 0; l < L_; l++) {
    const u16* wtq = Wt + (size_t)(l * 6 + 0) * D_ * D_;
    const u16* wtk = Wt + (size_t)(l * 6 + 1) * D_ * D_;
    const u16* wtv = Wt + (size_t)(l * 6 + 2) * D_ * D_;
    const u16* wto = Wt + (size_t)(l * 6 + 3) * D_ * D_;
    const u16* wt1 = Wt + (size_t)(l * 6 + 4) * D_ * D_;
    const u16* wt2 = Wt + (size_t)(l * 6 + 5) * D_ * D_;
    float* st = stats + l * 2048;

    k_gemm<<<ggrid, blk, 0, stream>>>(hb16, wtq, bq + l * D_, nullptr, qB, nullptr, 0);
    k_gemm<<<ggrid, blk, 0, stream>>>(hb16, wtk, bk + l * D_, nullptr, kB, nullptr, 0);
    k_gemm<<<ggrid, blk, 0, stream>>>(hb16, wtv, bv + l * D_, nullptr, vB, nullptr, 0);
    k_attn<<<B_ * H_, blk, 0, stream>>>(qB, kB, vB, aB);
    k_gemm<<<ggrid, blk, 0, stream>>>(aB, wto, bo + l * D_, hb16, nullptr, PB, 2);
    k_bnstats<<<512, blk, 0, stream>>>(PB, st);
    k_bnapply<<<65536, blk, 0, stream>>>(PB, st, g1 + l * D_, be1 + l * D_, hb16, nullptr);
    k_gemm<<<ggrid, blk, 0, stream>>>(hb16, wt1, b1 + l * FF_, nullptr, tB, nullptr, 1);
    k_gemm<<<ggrid, blk, 0, stream>>>(tB, wt2, b2 + l * D_, hb16, nullptr, PB, 2);
    k_bnstats<<<512, blk, 0, stream>>>(PB, st + 1024);
    if (l == L_ - 1)
      k_bnapply<<<65536, blk, 0, stream>>>(PB, st + 1024, g2 + l * D_, be2 + l * D_, nullptr, (float*)d_out);
    else
      k_bnapply<<<65536, blk, 0, stream>>>(PB, st + 1024, g2 + l * D_, be2 + l * D_, hb16, nullptr);
  }
}

// Round 3
// 2095.490 us; speedup vs baseline: 2.0645x; 2.0645x over previous
//
#include <hip/hip_runtime.h>

#define B_   128
#define S_   256
#define D_   512
#define L_   4
#define H_   8
#define DH_  64
#define FF_  512
#define M_   32768   // B_*S_
#define EPS_ 1e-3f

typedef unsigned short u16;
typedef unsigned int   u32;
typedef __bf16 bf16_8 __attribute__((ext_vector_type(8)));
typedef float  f32_4  __attribute__((ext_vector_type(4)));

__device__ __forceinline__ float bf2f(u16 u) {
  union { u32 i; float f; } x; x.i = ((u32)u) << 16; return x.f;
}
__device__ __forceinline__ u16 f2bf(float f) {
  union { float f; u32 i; } x; x.f = f;
  u32 r = x.i + 0x7fffu + ((x.i >> 16) & 1u);
  return (u16)(r >> 16);
}

// ---------------- embedding: h_bf16 = bf16(embed[seq] + pos), f32 inputs ----------------
__global__ __launch_bounds__(256) void k_embed(const int* __restrict__ seq,
    const float* __restrict__ pos, const float* __restrict__ emb,
    u16* __restrict__ h)
{
  int t = blockIdx.x * 256 + threadIdx.x;   // M_*64 threads, 8 elems each
  int row = t >> 6;
  int c = (t & 63) * 8;
  int s = row & (S_ - 1);
  int tok = seq[row];
  const float* ep = emb + (size_t)tok * D_ + c;
  const float* pp = pos + (size_t)s * D_ + c;
  float4 e0 = *(const float4*)ep;
  float4 e1 = *(const float4*)(ep + 4);
  float4 p0 = *(const float4*)pp;
  float4 p1 = *(const float4*)(pp + 4);
  u32 o[4];
  o[0] = (u32)f2bf(e0.x + p0.x) | ((u32)f2bf(e0.y + p0.y) << 16);
  o[1] = (u32)f2bf(e0.z + p0.z) | ((u32)f2bf(e0.w + p0.w) << 16);
  o[2] = (u32)f2bf(e1.x + p1.x) | ((u32)f2bf(e1.y + p1.y) << 16);
  o[3] = (u32)f2bf(e1.z + p1.z) | ((u32)f2bf(e1.w + p1.w) << 16);
  *(uint4*)&h[(size_t)row * D_ + c] = make_uint4(o[0], o[1], o[2], o[3]);
}

// ------- transpose all 24 [512x512] f32 weights -> bf16 Wt[n][k] -------
__global__ __launch_bounds__(256) void k_transpose(
    const float* __restrict__ Wq, const float* __restrict__ Wk, const float* __restrict__ Wv,
    const float* __restrict__ Wo, const float* __restrict__ W1, const float* __restrict__ W2,
    u16* __restrict__ Wt)
{
  __shared__ u16 tile[32][33];
  int mat = blockIdx.z;           // 0..23
  int layer = mat / 6, w = mat % 6;
  const float* src = (w == 0) ? Wq : (w == 1) ? Wk : (w == 2) ? Wv
                   : (w == 3) ? Wo : (w == 4) ? W1 : W2;
  src += (size_t)layer * (D_ * D_);
  u16* dst = Wt + (size_t)mat * (D_ * D_);
  int bx = blockIdx.x * 32;   // n
  int by = blockIdx.y * 32;   // k
  int tx = threadIdx.x & 31, ty = threadIdx.x >> 5;
#pragma unroll
  for (int i = 0; i < 32; i += 8)
    tile[ty + i][tx] = f2bf(src[(size_t)(by + ty + i) * D_ + bx + tx]);
  __syncthreads();
#pragma unroll
  for (int i = 0; i < 32; i += 8)
    dst[(size_t)(bx + ty + i) * D_ + by + tx] = tile[tx][ty + i];
}

// ---------------- GEMM: C[M,512] = A[M,512](bf16) x Bt[n][k](bf16) + bias(f32) ----------------
// mode 0: outb bf16 = A*B + bias
// mode 1: outb bf16 = relu(A*B + bias)
// mode 2: outf f32  = A*B + bias + resid(bf16)     (pre-BN buffer)
__global__ __launch_bounds__(256) void k_gemm(
    const u16* __restrict__ A, const u16* __restrict__ Bt,
    const float* __restrict__ bias, const u16* __restrict__ resid,
    u16* __restrict__ outb, float* __restrict__ outf, int mode)
{
  __shared__ u16 As[128][40];
  __shared__ u16 Bs[128][40];
  int tid = threadIdx.x;
  int m0 = blockIdx.x * 128;
  int n0 = blockIdx.y * 128;
  int wid = tid >> 6, lane = tid & 63;
  int wm = (wid >> 1) * 64, wn = (wid & 1) * 64;
  f32_4 acc[4][4] = {};
  int srow = tid >> 1;
  int scol = (tid & 1) * 16;
  const u16* Ap = A  + (size_t)(m0 + srow) * 512 + scol;
  const u16* Bp = Bt + (size_t)(n0 + srow) * 512 + scol;
  int fr = lane & 15;
  int fk = (lane >> 4) * 8;

  for (int k0 = 0; k0 < 512; k0 += 32) {
    uint4 a0 = *(const uint4*)(Ap + k0);
    uint4 a1 = *(const uint4*)(Ap + k0 + 8);
    uint4 b0 = *(const uint4*)(Bp + k0);
    uint4 b1 = *(const uint4*)(Bp + k0 + 8);
    __syncthreads();
    *(uint4*)&As[srow][scol]     = a0;
    *(uint4*)&As[srow][scol + 8] = a1;
    *(uint4*)&Bs[srow][scol]     = b0;
    *(uint4*)&Bs[srow][scol + 8] = b1;
    __syncthreads();
    bf16_8 afr[4], bfr[4];
#pragma unroll
    for (int i = 0; i < 4; i++) {
      afr[i] = *(const bf16_8*)&As[wm + i * 16 + fr][fk];
      bfr[i] = *(const bf16_8*)&Bs[wn + i * 16 + fr][fk];
    }
#pragma unroll
    for (int i = 0; i < 4; i++)
#pragma unroll
      for (int j = 0; j < 4; j++)
        acc[i][j] = __builtin_amdgcn_mfma_f32_16x16x32_bf16(afr[i], bfr[j], acc[i][j], 0, 0, 0);
  }

  int rbase = (lane >> 4) * 4;
#pragma unroll
  for (int j = 0; j < 4; j++) {
    int col = n0 + wn + j * 16 + fr;
    float bv = bias[col];
#pragma unroll
    for (int i = 0; i < 4; i++) {
      int row = m0 + wm + i * 16 + rbase;
#pragma unroll
      for (int r = 0; r < 4; r++) {
        float c = acc[i][j][r] + bv;
        if (mode == 1) c = fmaxf(c, 0.f);
        size_t idx = (size_t)(row + r) * 512 + col;
        if (mode == 2) {
          c += bf2f(resid[idx]);
          outf[idx] = c;
        } else {
          outb[idx] = f2bf(c);
        }
      }
    }
  }
}

// ---------------- MFMA attention ----------------
// grid: 4096 blocks = (b 0..127) x (h 0..7) x (qt 0..3); 4 waves, 16 q-rows/wave.
// LDS: Vt[d][key] and P[q][key], both bf16, stride 256, XOR-swizzled chunks
// (chunk ^= row&31) so ds_read_b128 frag reads stay conflict-free. 64 KB total.
__global__ __launch_bounds__(256) void k_attn(
    const u16* __restrict__ q, const u16* __restrict__ k,
    const u16* __restrict__ v, u16* __restrict__ attn)
{
  __shared__ u16 Vt[64 * 256];
  __shared__ u16 Pm[64 * 256];
  int tid = threadIdx.x;
  int bid = blockIdx.x;
  int qt = bid & 3, h = (bid >> 2) & 7, b = bid >> 5;

  // ---- stage V transposed: Vt[d][key], keys packed pairwise as u32 ----
  {
    int kp = tid & 127;          // key pair index (keys 2kp, 2kp+1)
    int o  = tid >> 7;           // d half (0: d 0..31, 1: d 32..63)
    const u16* vp = v + ((size_t)(b * S_ + 2 * kp)) * D_ + h * DH_ + o * 32;
    union { uint4 u[4]; u16 s[32]; } r0, r1;
#pragma unroll
    for (int i = 0; i < 4; i++) {
      r0.u[i] = *(const uint4*)(vp + i * 8);
      r1.u[i] = *(const uint4*)(vp + D_ + i * 8);
    }
#pragma unroll
    for (int d = 0; d < 32; d++) {
      int da = o * 32 + d;
      u32 val = (u32)r0.s[d] | ((u32)r1.s[d] << 16);
      int idx = da * 256 + ((((kp >> 2) ^ (da & 31)) << 3)) + ((2 * kp) & 7);
      *(u32*)&Vt[idx] = val;
    }
  }
  __syncthreads();

  int w = tid >> 6, lane = tid & 63;
  int lr = lane & 15;          // fragment row/col
  int lk = lane >> 4;          // k-group
  int rbase = lk * 4;
  int q0 = qt * 64 + w * 16;   // sequence-local q-row base of this wave

  // ---- QK^T: S[16 x 256] per wave, in registers ----
  f32_4 accS[16];
  const u16* qbase = q + ((size_t)(b * S_ + q0 + lr)) * D_ + h * DH_ + lk * 8;
  bf16_8 af0 = *(const bf16_8*)(qbase);
  bf16_8 af1 = *(const bf16_8*)(qbase + 32);
#pragma unroll
  for (int j = 0; j < 16; j++) {
    const u16* kbase = k + ((size_t)(b * S_ + j * 16 + lr)) * D_ + h * DH_ + lk * 8;
    bf16_8 bf0 = *(const bf16_8*)(kbase);
    bf16_8 bf1 = *(const bf16_8*)(kbase + 32);
    f32_4 z = {};
    z = __builtin_amdgcn_mfma_f32_16x16x32_bf16(af0, bf0, z, 0, 0, 0);
    accS[j] = __builtin_amdgcn_mfma_f32_16x16x32_bf16(af1, bf1, z, 0, 0, 0);
  }

  // ---- softmax over keys (row = rbase + r, cols spread over j and lane&15) ----
  float l[4];
#pragma unroll
  for (int r = 0; r < 4; r++) {
    float m = accS[0][r];
#pragma unroll
    for (int j = 1; j < 16; j++) m = fmaxf(m, accS[j][r]);
    m = fmaxf(m, __shfl_xor(m, 1));
    m = fmaxf(m, __shfl_xor(m, 2));
    m = fmaxf(m, __shfl_xor(m, 4));
    m = fmaxf(m, __shfl_xor(m, 8));
    float s = 0.f;
#pragma unroll
    for (int j = 0; j < 16; j++) {
      float p = __expf((accS[j][r] - m) * 0.125f);   // 1/sqrt(64)
      accS[j][r] = p;
      s += p;
    }
    s += __shfl_xor(s, 1);
    s += __shfl_xor(s, 2);
    s += __shfl_xor(s, 4);
    s += __shfl_xor(s, 8);
    l[r] = s;
  }

  // ---- write P (bf16) to LDS: C-layout -> memory, own rows only ----
#pragma unroll
  for (int j = 0; j < 16; j++) {
    int col = j * 16 + lr;
    int ch = col >> 3, cl = col & 7;
#pragma unroll
    for (int r = 0; r < 4; r++) {
      int row = w * 16 + rbase + r;
      Pm[row * 256 + ((ch ^ (row & 31)) << 3) + cl] = f2bf(accS[j][r]);
    }
  }

  // ---- PV: O[16 x 64] per wave ----
  f32_4 accO[4] = {};
#pragma unroll
  for (int kk = 0; kk < 8; kk++) {
    int arow = w * 16 + lr;
    int ach = kk * 4 + lk;
    bf16_8 pa = *(const bf16_8*)&Pm[arow * 256 + ((ach ^ (arow & 31)) << 3)];
#pragma unroll
    for (int jd = 0; jd < 4; jd++) {
      int brow = jd * 16 + lr;
      bf16_8 vb = *(const bf16_8*)&Vt[brow * 256 + ((ach ^ (brow & 31)) << 3)];
      accO[jd] = __builtin_amdgcn_mfma_f32_16x16x32_bf16(pa, vb, accO[jd], 0, 0, 0);
    }
  }

  // ---- epilogue: normalize by l, store bf16 ----
  float linv[4];
#pragma unroll
  for (int r = 0; r < 4; r++) linv[r] = 1.f / l[r];
  size_t orow0 = (size_t)(b * S_ + q0 + rbase);
#pragma unroll
  for (int jd = 0; jd < 4; jd++) {
    int col = h * DH_ + jd * 16 + lr;
#pragma unroll
    for (int r = 0; r < 4; r++)
      attn[(orow0 + r) * D_ + col] = f2bf(accO[jd][r] * linv[r]);
  }
}

// ---------------- batchnorm ----------------
__global__ __launch_bounds__(256) void k_zero(float* p, int n) {
  int t = blockIdx.x * 256 + threadIdx.x;
  if (t < n) p[t] = 0.f;
}

__global__ __launch_bounds__(256) void k_bnstats(const float* __restrict__ P,
                                                 float* __restrict__ stats) {
  int tid = threadIdx.x;
  size_t row0 = (size_t)blockIdx.x * 64;
  float s0 = 0, q0 = 0, s1 = 0, q1 = 0;
  for (int r = 0; r < 64; r++) {
    const float* p = P + (row0 + r) * 512;
    float a = p[tid], b = p[tid + 256];
    s0 += a; q0 = fmaf(a, a, q0);
    s1 += b; q1 = fmaf(b, b, q1);
  }
  atomicAdd(&stats[tid], s0);
  atomicAdd(&stats[tid + 256], s1);
  atomicAdd(&stats[512 + tid], q0);
  atomicAdd(&stats[512 + tid + 256], q1);
}

// writes bf16 (outb) when outf==nullptr, else f32 to outf (final layer -> d_out)
__global__ __launch_bounds__(256) void k_bnapply(const float* __restrict__ P,
    const float* __restrict__ stats, const float* __restrict__ gamma,
    const float* __restrict__ beta, u16* __restrict__ outb, float* __restrict__ outf)
{
  size_t t = (size_t)blockIdx.x * 256 + threadIdx.x;
  int f = (int)(t & 511);
  const float inv = 1.f / 32768.f;
  float mu = stats[f] * inv;
  float var = stats[512 + f] * inv - mu * mu;
  float sc = gamma[f] * rsqrtf(var + EPS_);
  float sh = beta[f] - mu * sc;
  float val = P[t] * sc + sh;
  if (outf) outf[t] = val;
  else      outb[t] = f2bf(val);
}

// ---------------- launch ----------------
extern "C" void kernel_launch(void* const* d_in, const int* in_sizes, int n_in,
                              void* d_out, int out_size, void* d_ws, size_t ws_size,
                              hipStream_t stream)
{
  const int*   seq = (const int*)d_in[0];
  const float* pos = (const float*)d_in[1];
  const float* emb = (const float*)d_in[2];
  const float* Wq  = (const float*)d_in[3];
  const float* bq  = (const float*)d_in[4];
  const float* Wk  = (const float*)d_in[5];
  const float* bk  = (const float*)d_in[6];
  const float* Wv  = (const float*)d_in[7];
  const float* bv  = (const float*)d_in[8];
  const float* Wo  = (const float*)d_in[9];
  const float* bo  = (const float*)d_in[10];
  const float* g1  = (const float*)d_in[11];
  const float* be1 = (const float*)d_in[12];
  const float* W1  = (const float*)d_in[13];
  const float* b1  = (const float*)d_in[14];
  const float* W2  = (const float*)d_in[15];
  const float* b2  = (const float*)d_in[16];
  const float* g2  = (const float*)d_in[17];
  const float* be2 = (const float*)d_in[18];

  char* ws = (char*)d_ws;
  const size_t SZH = (size_t)M_ * D_ * 2;        // 32 MiB per bf16 activation
  u16* hb16 = (u16*)(ws);                        // master activation (bf16)
  u16* qB   = (u16*)(ws + SZH);
  u16* kB   = (u16*)(ws + 2 * SZH);
  u16* vB   = (u16*)(ws + 3 * SZH);
  u16* aB   = (u16*)(ws + 4 * SZH);
  float* PB = (float*)(ws + 2 * SZH);            // f32 pre-BN, overlays kB,vB (dead then)
  u16* tB   = qB;                                // FFN hidden reuses q
  u16* Wt   = (u16*)(ws + 5 * SZH);
  float* stats = (float*)(ws + 5 * SZH + (size_t)24 * D_ * D_ * 2);

  dim3 blk(256);
  k_zero<<<32, blk, 0, stream>>>(stats, 8192);
  k_transpose<<<dim3(16, 16, 24), blk, 0, stream>>>(Wq, Wk, Wv, Wo, W1, W2, Wt);
  k_embed<<<M_ * 64 / 256, blk, 0, stream>>>(seq, pos, emb, hb16);

  dim3 ggrid(M_ / 128, 512 / 128);
  for (int l = 0; l < L_; l++) {
    const u16* wtq = Wt + (size_t)(l * 6 + 0) * D_ * D_;
    const u16* wtk = Wt + (size_t)(l * 6 + 1) * D_ * D_;
    const u16* wtv = Wt + (size_t)(l * 6 + 2) * D_ * D_;
    const u16* wto = Wt + (size_t)(l * 6 + 3) * D_ * D_;
    const u16* wt1 = Wt + (size_t)(l * 6 + 4) * D_ * D_;
    const u16* wt2 = Wt + (size_t)(l * 6 + 5) * D_ * D_;
    float* st = stats + l * 2048;

    k_gemm<<<ggrid, blk, 0, stream>>>(hb16, wtq, bq + l * D_, nullptr, qB, nullptr, 0);
    k_gemm<<<ggrid, blk, 0, stream>>>(hb16, wtk, bk + l * D_, nullptr, kB, nullptr, 0);
    k_gemm<<<ggrid, blk, 0, stream>>>(hb16, wtv, bv + l * D_, nullptr, vB, nullptr, 0);
    k_attn<<<4096, blk, 0, stream>>>(qB, kB, vB, aB);
    k_gemm<<<ggrid, blk, 0, stream>>>(aB, wto, bo + l * D_, hb16, nullptr, PB, 2);
    k_bnstats<<<512, blk, 0, stream>>>(PB, st);
    k_bnapply<<<65536, blk, 0, stream>>>(PB, st, g1 + l * D_, be1 + l * D_, hb16, nullptr);
    k_gemm<<<ggrid, blk, 0, stream>>>(hb16, wt1, b1 + l * FF_, nullptr, tB, nullptr, 1);
    k_gemm<<<ggrid, blk, 0, stream>>>(tB, wt2, b2 + l * D_, hb16, nullptr, PB, 2);
    k_bnstats<<<512, blk, 0, stream>>>(PB, st + 1024);
    if (l == L_ - 1)
      k_bnapply<<<65536, blk, 0, stream>>>(PB, st + 1024, g2 + l * D_, be2 + l * D_, nullptr, (float*)d_out);
    else
      k_bnapply<<<65536, blk, 0, stream>>>(PB, st + 1024, g2 + l * D_, be2 + l * D_, hb16, nullptr);
  }
}

// Round 4
// 2091.550 us; speedup vs baseline: 2.0684x; 1.0019x over previous
//
#include <hip/hip_runtime.h>

#define B_   128
#define S_   256
#define D_   512
#define L_   4
#define H_   8
#define DH_  64
#define FF_  512
#define M_   32768   // B_*S_
#define EPS_ 1e-3f

typedef unsigned short u16;
typedef unsigned int   u32;
typedef __bf16 bf16_8 __attribute__((ext_vector_type(8)));
typedef float  f32_4  __attribute__((ext_vector_type(4)));

__device__ __forceinline__ float bf2f(u16 u) {
  union { u32 i; float f; } x; x.i = ((u32)u) << 16; return x.f;
}
__device__ __forceinline__ u16 f2bf(float f) {
  union { float f; u32 i; } x; x.f = f;
  u32 r = x.i + 0x7fffu + ((x.i >> 16) & 1u);
  return (u16)(r >> 16);
}
// async 16B global->LDS; lane i of the wave lands at l + i*16 bytes
__device__ __forceinline__ void async_cp16(const void* g, void* l) {
  __builtin_amdgcn_global_load_lds(
      (const __attribute__((address_space(1))) void*)g,
      (__attribute__((address_space(3))) void*)l, 16, 0, 0);
}

// ---------------- embedding: h_bf16 = bf16(embed[seq] + pos), f32 inputs ----------------
__global__ __launch_bounds__(256) void k_embed(const int* __restrict__ seq,
    const float* __restrict__ pos, const float* __restrict__ emb,
    u16* __restrict__ h)
{
  int t = blockIdx.x * 256 + threadIdx.x;   // M_*64 threads, 8 elems each
  int row = t >> 6;
  int c = (t & 63) * 8;
  int s = row & (S_ - 1);
  int tok = seq[row];
  const float* ep = emb + (size_t)tok * D_ + c;
  const float* pp = pos + (size_t)s * D_ + c;
  float4 e0 = *(const float4*)ep;
  float4 e1 = *(const float4*)(ep + 4);
  float4 p0 = *(const float4*)pp;
  float4 p1 = *(const float4*)(pp + 4);
  u32 o[4];
  o[0] = (u32)f2bf(e0.x + p0.x) | ((u32)f2bf(e0.y + p0.y) << 16);
  o[1] = (u32)f2bf(e0.z + p0.z) | ((u32)f2bf(e0.w + p0.w) << 16);
  o[2] = (u32)f2bf(e1.x + p1.x) | ((u32)f2bf(e1.y + p1.y) << 16);
  o[3] = (u32)f2bf(e1.z + p1.z) | ((u32)f2bf(e1.w + p1.w) << 16);
  *(uint4*)&h[(size_t)row * D_ + c] = make_uint4(o[0], o[1], o[2], o[3]);
}

// ------- transpose all 24 [512x512] f32 weights -> bf16 Wt[n][k] -------
__global__ __launch_bounds__(256) void k_transpose(
    const float* __restrict__ Wq, const float* __restrict__ Wk, const float* __restrict__ Wv,
    const float* __restrict__ Wo, const float* __restrict__ W1, const float* __restrict__ W2,
    u16* __restrict__ Wt)
{
  __shared__ u16 tile[32][33];
  int mat = blockIdx.z;           // 0..23
  int layer = mat / 6, w = mat % 6;
  const float* src = (w == 0) ? Wq : (w == 1) ? Wk : (w == 2) ? Wv
                   : (w == 3) ? Wo : (w == 4) ? W1 : W2;
  src += (size_t)layer * (D_ * D_);
  u16* dst = Wt + (size_t)mat * (D_ * D_);
  int bx = blockIdx.x * 32;   // n
  int by = blockIdx.y * 32;   // k
  int tx = threadIdx.x & 31, ty = threadIdx.x >> 5;
#pragma unroll
  for (int i = 0; i < 32; i += 8)
    tile[ty + i][tx] = f2bf(src[(size_t)(by + ty + i) * D_ + bx + tx]);
  __syncthreads();
#pragma unroll
  for (int i = 0; i < 32; i += 8)
    dst[(size_t)(bx + ty + i) * D_ + by + tx] = tile[tx][ty + i];
}

// ---------------- GEMM: C[M,512] = A[M,512](bf16) x Bt[n][k](bf16) + bias(f32) ----------------
// mode 0: outb bf16 = A*B + bias                      (row-major [M,512])
// mode 1: outb bf16 = relu(A*B + bias)                (row-major [M,512])
// mode 2: outf f32  = A*B + bias + resid(bf16), fused BN-stat atomics into stats[]
// mode 3: outb bf16 = A*B + bias, head-blocked [b,h,s,dh] (for q/k/v)
// Staging: global_load_lds 16B/lane into unpadded [128][32] tiles; chunk XOR-swizzled
// on the global side so frag ds_read_b128 is 2-way-aliased (free).
__global__ __launch_bounds__(256) void k_gemm(
    const u16* __restrict__ A, const u16* __restrict__ Bt,
    const float* __restrict__ bias, const u16* __restrict__ resid,
    u16* __restrict__ outb, float* __restrict__ outf, float* __restrict__ stats,
    int mode)
{
  __shared__ u16 As[128 * 32];
  __shared__ u16 Bs[128 * 32];
  int tid = threadIdx.x;
  int m0 = blockIdx.x * 128;
  int n0 = blockIdx.y * 128;
  int w = tid >> 6, lane = tid & 63;
  int wm = (w >> 1) * 64, wn = (w & 1) * 64;
  int fr = lane & 15, lk = lane >> 4;

  // staging: wave w stages rows [w*32, w*32+32) of A and B tiles via 2 cp16 each.
  int srow = lane >> 2;                          // 0..15 within 16-row window
  int schunk = (lane & 3) ^ ((lane >> 4) & 3);   // swizzled 16B chunk within 64B row
  const u16* Ag0 = A  + (size_t)(m0 + w * 32 + srow) * 512 + schunk * 8;
  const u16* Ag1 = Ag0 + (size_t)16 * 512;
  const u16* Bg0 = Bt + (size_t)(n0 + w * 32 + srow) * 512 + schunk * 8;
  const u16* Bg1 = Bg0 + (size_t)16 * 512;
  u16* Al0 = &As[(w * 32) * 32];
  u16* Al1 = &As[(w * 32 + 16) * 32];
  u16* Bl0 = &Bs[(w * 32) * 32];
  u16* Bl1 = &Bs[(w * 32 + 16) * 32];

  f32_4 acc[4][4] = {};
  int ach = (lk ^ ((fr >> 2) & 3)) * 8;          // frag chunk (elements) after swizzle

  for (int k0 = 0; k0 < 512; k0 += 32) {
    async_cp16(Ag0 + k0, Al0);
    async_cp16(Ag1 + k0, Al1);
    async_cp16(Bg0 + k0, Bl0);
    async_cp16(Bg1 + k0, Bl1);
    __syncthreads();                             // drains vmcnt + barrier
    bf16_8 afr[4], bfr[4];
#pragma unroll
    for (int i = 0; i < 4; i++) {
      afr[i] = *(const bf16_8*)&As[(wm + i * 16 + fr) * 32 + ach];
      bfr[i] = *(const bf16_8*)&Bs[(wn + i * 16 + fr) * 32 + ach];
    }
#pragma unroll
    for (int i = 0; i < 4; i++)
#pragma unroll
      for (int j = 0; j < 4; j++)
        acc[i][j] = __builtin_amdgcn_mfma_f32_16x16x32_bf16(afr[i], bfr[j], acc[i][j], 0, 0, 0);
    __syncthreads();
  }

  int rbase = lk * 4;
#pragma unroll
  for (int j = 0; j < 4; j++) {
    int col = n0 + wn + j * 16 + fr;
    float bv = bias[col];
    float csum = 0.f, csq = 0.f;
#pragma unroll
    for (int i = 0; i < 4; i++) {
      int row = m0 + wm + i * 16 + rbase;
#pragma unroll
      for (int r = 0; r < 4; r++) {
        float c = acc[i][j][r] + bv;
        if (mode == 1) c = fmaxf(c, 0.f);
        if (mode == 2) {
          size_t idx = (size_t)(row + r) * 512 + col;
          c += bf2f(resid[idx]);
          outf[idx] = c;
          csum += c; csq = fmaf(c, c, csq);
        } else if (mode == 3) {
          int rr = row + r;    // global M-row = b*256+s ; col = h*64+dh
          size_t idx = ((size_t)((rr >> 8) * 8 + (col >> 6)) * 256 + (rr & 255)) * 64 + (col & 63);
          outb[idx] = f2bf(c);
        } else {
          outb[(size_t)(row + r) * 512 + col] = f2bf(c);
        }
      }
    }
    if (mode == 2) {
      csum += __shfl_xor(csum, 16); csum += __shfl_xor(csum, 32);
      csq  += __shfl_xor(csq, 16);  csq  += __shfl_xor(csq, 32);
      if (lk == 0) {
        atomicAdd(&stats[col], csum);
        atomicAdd(&stats[512 + col], csq);
      }
    }
  }
}

// ---------------- MFMA attention ----------------
// q/k/v are head-blocked [b,h,s,dh] (64-elem rows). attn out is row-major [M,512].
// grid: 4096 blocks = (b,h,qt); 4 waves, 16 q-rows/wave.
__global__ __launch_bounds__(256) void k_attn(
    const u16* __restrict__ q, const u16* __restrict__ k,
    const u16* __restrict__ v, u16* __restrict__ attn)
{
  __shared__ u16 Vt[64 * 256];
  __shared__ u16 Pm[64 * 256];
  int tid = threadIdx.x;
  int bid = blockIdx.x;
  int qt = bid & 3, h = (bid >> 2) & 7, b = bid >> 5;
  size_t hb = (size_t)(b * 8 + h) * (256 * 64);

  // ---- stage V transposed: Vt[d][key], keys packed pairwise as u32 ----
  {
    int kp = tid & 127;          // key pair index (keys 2kp, 2kp+1)
    int o  = tid >> 7;           // d half (0: d 0..31, 1: d 32..63)
    const u16* vp = v + hb + (size_t)(2 * kp) * 64 + o * 32;
    union { uint4 u[4]; u16 s[32]; } r0, r1;
#pragma unroll
    for (int i = 0; i < 4; i++) {
      r0.u[i] = *(const uint4*)(vp + i * 8);
      r1.u[i] = *(const uint4*)(vp + 64 + i * 8);
    }
#pragma unroll
    for (int d = 0; d < 32; d++) {
      int da = o * 32 + d;
      u32 val = (u32)r0.s[d] | ((u32)r1.s[d] << 16);
      int idx = da * 256 + ((((kp >> 2) ^ (da & 31)) << 3)) + ((2 * kp) & 7);
      *(u32*)&Vt[idx] = val;
    }
  }
  __syncthreads();

  int w = tid >> 6, lane = tid & 63;
  int lr = lane & 15;          // fragment row/col
  int lk = lane >> 4;          // k-group
  int rbase = lk * 4;
  int q0 = qt * 64 + w * 16;   // sequence-local q-row base of this wave

  // ---- QK^T: S[16 x 256] per wave, in registers ----
  f32_4 accS[16];
  const u16* qbase = q + hb + (size_t)(q0 + lr) * 64 + lk * 8;
  bf16_8 af0 = *(const bf16_8*)(qbase);
  bf16_8 af1 = *(const bf16_8*)(qbase + 32);
#pragma unroll
  for (int j = 0; j < 16; j++) {
    const u16* kbase = k + hb + (size_t)(j * 16 + lr) * 64 + lk * 8;
    bf16_8 bf0 = *(const bf16_8*)(kbase);
    bf16_8 bf1 = *(const bf16_8*)(kbase + 32);
    f32_4 z = {};
    z = __builtin_amdgcn_mfma_f32_16x16x32_bf16(af0, bf0, z, 0, 0, 0);
    accS[j] = __builtin_amdgcn_mfma_f32_16x16x32_bf16(af1, bf1, z, 0, 0, 0);
  }

  // ---- softmax over keys ----
  float l[4];
#pragma unroll
  for (int r = 0; r < 4; r++) {
    float m = accS[0][r];
#pragma unroll
    for (int j = 1; j < 16; j++) m = fmaxf(m, accS[j][r]);
    m = fmaxf(m, __shfl_xor(m, 1));
    m = fmaxf(m, __shfl_xor(m, 2));
    m = fmaxf(m, __shfl_xor(m, 4));
    m = fmaxf(m, __shfl_xor(m, 8));
    float s = 0.f;
#pragma unroll
    for (int j = 0; j < 16; j++) {
      float p = __expf((accS[j][r] - m) * 0.125f);   // 1/sqrt(64)
      accS[j][r] = p;
      s += p;
    }
    s += __shfl_xor(s, 1);
    s += __shfl_xor(s, 2);
    s += __shfl_xor(s, 4);
    s += __shfl_xor(s, 8);
    l[r] = s;
  }

  // ---- write P (bf16) to LDS: C-layout -> memory, own rows only ----
#pragma unroll
  for (int j = 0; j < 16; j++) {
    int col = j * 16 + lr;
    int ch = col >> 3, cl = col & 7;
#pragma unroll
    for (int r = 0; r < 4; r++) {
      int row = w * 16 + rbase + r;
      Pm[row * 256 + ((ch ^ (row & 31)) << 3) + cl] = f2bf(accS[j][r]);
    }
  }

  // ---- PV: O[16 x 64] per wave ----
  f32_4 accO[4] = {};
#pragma unroll
  for (int kk = 0; kk < 8; kk++) {
    int arow = w * 16 + lr;
    int ach = kk * 4 + lk;
    bf16_8 pa = *(const bf16_8*)&Pm[arow * 256 + ((ach ^ (arow & 31)) << 3)];
#pragma unroll
    for (int jd = 0; jd < 4; jd++) {
      int brow = jd * 16 + lr;
      bf16_8 vb = *(const bf16_8*)&Vt[brow * 256 + ((ach ^ (brow & 31)) << 3)];
      accO[jd] = __builtin_amdgcn_mfma_f32_16x16x32_bf16(pa, vb, accO[jd], 0, 0, 0);
    }
  }

  // ---- epilogue: normalize by l, store bf16 to [M,512] ----
  float linv[4];
#pragma unroll
  for (int r = 0; r < 4; r++) linv[r] = 1.f / l[r];
  size_t orow0 = (size_t)(b * S_ + q0 + rbase);
#pragma unroll
  for (int jd = 0; jd < 4; jd++) {
    int col = h * DH_ + jd * 16 + lr;
#pragma unroll
    for (int r = 0; r < 4; r++)
      attn[(orow0 + r) * D_ + col] = f2bf(accO[jd][r] * linv[r]);
  }
}

// ---------------- batchnorm ----------------
__global__ __launch_bounds__(256) void k_zero(float* p, int n) {
  int t = blockIdx.x * 256 + threadIdx.x;
  if (t < n) p[t] = 0.f;
}

// writes bf16 (outb) when outf==nullptr, else f32 to outf (final layer -> d_out)
__global__ __launch_bounds__(256) void k_bnapply(const float* __restrict__ P,
    const float* __restrict__ stats, const float* __restrict__ gamma,
    const float* __restrict__ beta, u16* __restrict__ outb, float* __restrict__ outf)
{
  size_t t = (size_t)blockIdx.x * 256 + threadIdx.x;
  int f = (int)(t & 511);
  const float inv = 1.f / 32768.f;
  float mu = stats[f] * inv;
  float var = stats[512 + f] * inv - mu * mu;
  float sc = gamma[f] * rsqrtf(var + EPS_);
  float sh = beta[f] - mu * sc;
  float val = P[t] * sc + sh;
  if (outf) outf[t] = val;
  else      outb[t] = f2bf(val);
}

// ---------------- launch ----------------
extern "C" void kernel_launch(void* const* d_in, const int* in_sizes, int n_in,
                              void* d_out, int out_size, void* d_ws, size_t ws_size,
                              hipStream_t stream)
{
  const int*   seq = (const int*)d_in[0];
  const float* pos = (const float*)d_in[1];
  const float* emb = (const float*)d_in[2];
  const float* Wq  = (const float*)d_in[3];
  const float* bq  = (const float*)d_in[4];
  const float* Wk  = (const float*)d_in[5];
  const float* bk  = (const float*)d_in[6];
  const float* Wv  = (const float*)d_in[7];
  const float* bv  = (const float*)d_in[8];
  const float* Wo  = (const float*)d_in[9];
  const float* bo  = (const float*)d_in[10];
  const float* g1  = (const float*)d_in[11];
  const float* be1 = (const float*)d_in[12];
  const float* W1  = (const float*)d_in[13];
  const float* b1  = (const float*)d_in[14];
  const float* W2  = (const float*)d_in[15];
  const float* b2  = (const float*)d_in[16];
  const float* g2  = (const float*)d_in[17];
  const float* be2 = (const float*)d_in[18];

  char* ws = (char*)d_ws;
  const size_t SZH = (size_t)M_ * D_ * 2;        // 32 MiB per bf16 activation
  u16* hb16 = (u16*)(ws);                        // master activation (bf16)
  u16* qB   = (u16*)(ws + SZH);
  u16* kB   = (u16*)(ws + 2 * SZH);
  u16* vB   = (u16*)(ws + 3 * SZH);
  u16* aB   = (u16*)(ws + 4 * SZH);
  float* PB = (float*)(ws + 2 * SZH);            // f32 pre-BN, overlays kB,vB (dead then)
  u16* tB   = qB;                                // FFN hidden reuses q
  u16* Wt   = (u16*)(ws + 5 * SZH);
  float* stats = (float*)(ws + 5 * SZH + (size_t)24 * D_ * D_ * 2);

  dim3 blk(256);
  k_zero<<<32, blk, 0, stream>>>(stats, 8192);
  k_transpose<<<dim3(16, 16, 24), blk, 0, stream>>>(Wq, Wk, Wv, Wo, W1, W2, Wt);
  k_embed<<<M_ * 64 / 256, blk, 0, stream>>>(seq, pos, emb, hb16);

  dim3 ggrid(M_ / 128, 512 / 128);
  for (int l = 0; l < L_; l++) {
    const u16* wtq = Wt + (size_t)(l * 6 + 0) * D_ * D_;
    const u16* wtk = Wt + (size_t)(l * 6 + 1) * D_ * D_;
    const u16* wtv = Wt + (size_t)(l * 6 + 2) * D_ * D_;
    const u16* wto = Wt + (size_t)(l * 6 + 3) * D_ * D_;
    const u16* wt1 = Wt + (size_t)(l * 6 + 4) * D_ * D_;
    const u16* wt2 = Wt + (size_t)(l * 6 + 5) * D_ * D_;
    float* st = stats + l * 2048;

    k_gemm<<<ggrid, blk, 0, stream>>>(hb16, wtq, bq + l * D_, nullptr, qB, nullptr, nullptr, 3);
    k_gemm<<<ggrid, blk, 0, stream>>>(hb16, wtk, bk + l * D_, nullptr, kB, nullptr, nullptr, 3);
    k_gemm<<<ggrid, blk, 0, stream>>>(hb16, wtv, bv + l * D_, nullptr, vB, nullptr, nullptr, 3);
    k_attn<<<4096, blk, 0, stream>>>(qB, kB, vB, aB);
    k_gemm<<<ggrid, blk, 0, stream>>>(aB, wto, bo + l * D_, hb16, nullptr, PB, st, 2);
    k_bnapply<<<65536, blk, 0, stream>>>(PB, st, g1 + l * D_, be1 + l * D_, hb16, nullptr);
    k_gemm<<<ggrid, blk, 0, stream>>>(hb16, wt1, b1 + l * FF_, nullptr, tB, nullptr, nullptr, 1);
    k_gemm<<<ggrid, blk, 0, stream>>>(tB, wt2, b2 + l * D_, hb16, nullptr, PB, st + 1024, 2);
    if (l == L_ - 1)
      k_bnapply<<<65536, blk, 0, stream>>>(PB, st + 1024, g2 + l * D_, be2 + l * D_, nullptr, (float*)d_out);
    else
      k_bnapply<<<65536, blk, 0, stream>>>(PB, st + 1024, g2 + l * D_, be2 + l * D_, hb16, nullptr);
  }
}

// Round 5
// 1981.884 us; speedup vs baseline: 2.1828x; 1.0553x over previous
//
#include <hip/hip_runtime.h>

#define B_   128
#define S_   256
#define D_   512
#define L_   4
#define H_   8
#define DH_  64
#define FF_  512
#define M_   32768   // B_*S_
#define EPS_ 1e-3f

typedef unsigned short u16;
typedef unsigned int   u32;
typedef __bf16 bf16_8 __attribute__((ext_vector_type(8)));
typedef float  f32_4  __attribute__((ext_vector_type(4)));

__device__ __forceinline__ float bf2f(u16 u) {
  union { u32 i; float f; } x; x.i = ((u32)u) << 16; return x.f;
}
__device__ __forceinline__ u16 f2bf(float f) {
  union { float f; u32 i; } x; x.f = f;
  u32 r = x.i + 0x7fffu + ((x.i >> 16) & 1u);
  return (u16)(r >> 16);
}
// async 16B global->LDS; lane i of the wave lands at l + i*16 bytes
__device__ __forceinline__ void async_cp16(const void* g, void* l) {
  __builtin_amdgcn_global_load_lds(
      (const __attribute__((address_space(1))) void*)g,
      (__attribute__((address_space(3))) void*)l, 16, 0, 0);
}

// ---------------- embedding: h_bf16 = bf16(embed[seq] + pos), f32 inputs ----------------
__global__ __launch_bounds__(256) void k_embed(const int* __restrict__ seq,
    const float* __restrict__ pos, const float* __restrict__ emb,
    u16* __restrict__ h)
{
  int t = blockIdx.x * 256 + threadIdx.x;   // M_*64 threads, 8 elems each
  int row = t >> 6;
  int c = (t & 63) * 8;
  int s = row & (S_ - 1);
  int tok = seq[row];
  const float* ep = emb + (size_t)tok * D_ + c;
  const float* pp = pos + (size_t)s * D_ + c;
  float4 e0 = *(const float4*)ep;
  float4 e1 = *(const float4*)(ep + 4);
  float4 p0 = *(const float4*)pp;
  float4 p1 = *(const float4*)(pp + 4);
  u32 o[4];
  o[0] = (u32)f2bf(e0.x + p0.x) | ((u32)f2bf(e0.y + p0.y) << 16);
  o[1] = (u32)f2bf(e0.z + p0.z) | ((u32)f2bf(e0.w + p0.w) << 16);
  o[2] = (u32)f2bf(e1.x + p1.x) | ((u32)f2bf(e1.y + p1.y) << 16);
  o[3] = (u32)f2bf(e1.z + p1.z) | ((u32)f2bf(e1.w + p1.w) << 16);
  *(uint4*)&h[(size_t)row * D_ + c] = make_uint4(o[0], o[1], o[2], o[3]);
}

// ------- transpose all 24 [512x512] f32 weights -> bf16 Wt[n][k] -------
__global__ __launch_bounds__(256) void k_transpose(
    const float* __restrict__ Wq, const float* __restrict__ Wk, const float* __restrict__ Wv,
    const float* __restrict__ Wo, const float* __restrict__ W1, const float* __restrict__ W2,
    u16* __restrict__ Wt)
{
  __shared__ u16 tile[32][33];
  int mat = blockIdx.z;           // 0..23
  int layer = mat / 6, w = mat % 6;
  const float* src = (w == 0) ? Wq : (w == 1) ? Wk : (w == 2) ? Wv
                   : (w == 3) ? Wo : (w == 4) ? W1 : W2;
  src += (size_t)layer * (D_ * D_);
  u16* dst = Wt + (size_t)mat * (D_ * D_);
  int bx = blockIdx.x * 32;   // n
  int by = blockIdx.y * 32;   // k
  int tx = threadIdx.x & 31, ty = threadIdx.x >> 5;
#pragma unroll
  for (int i = 0; i < 32; i += 8)
    tile[ty + i][tx] = f2bf(src[(size_t)(by + ty + i) * D_ + bx + tx]);
  __syncthreads();
#pragma unroll
  for (int i = 0; i < 32; i += 8)
    dst[(size_t)(bx + ty + i) * D_ + by + tx] = tile[tx][ty + i];
}

// ---------------- GEMM: C[M,512] = A[M,512](bf16) x Bt[n][k](bf16) + bias(f32) ----------------
// mode 0: outb bf16 = A*B + bias                      (row-major [M,512])
// mode 1: outb bf16 = relu(A*B + bias)                (row-major [M,512])
// mode 2: outf f32  = A*B + bias + resid(bf16), fused BN-stat atomics into stats[]
// mode 3: outb bf16 = A*B + bias, head-blocked [b,h,s,dh] (for q/k/v)
// Double-buffered K-loop: prefetch for iter k+1 issued right after the single
// barrier of iter k, so the next barrier's vmcnt(0) drain overlaps compute.
__global__ __launch_bounds__(256) void k_gemm(
    const u16* __restrict__ A, const u16* __restrict__ Bt,
    const float* __restrict__ bias, const u16* __restrict__ resid,
    u16* __restrict__ outb, float* __restrict__ outf, float* __restrict__ stats,
    int mode)
{
  __shared__ u16 As[2 * 128 * 32];
  __shared__ u16 Bs[2 * 128 * 32];
  int tid = threadIdx.x;
  int m0 = blockIdx.x * 128;
  int n0 = blockIdx.y * 128;
  int w = tid >> 6, lane = tid & 63;
  int wm = (w >> 1) * 64, wn = (w & 1) * 64;
  int fr = lane & 15, lk = lane >> 4;

  // staging: wave w stages rows [w*32, w*32+32) of A and B tiles via 2 cp16 each.
  int srow = lane >> 2;                          // 0..15 within 16-row window
  int schunk = (lane & 3) ^ ((lane >> 4) & 3);   // swizzled 16B chunk within 64B row
  const u16* Ag0 = A  + (size_t)(m0 + w * 32 + srow) * 512 + schunk * 8;
  const u16* Ag1 = Ag0 + (size_t)16 * 512;
  const u16* Bg0 = Bt + (size_t)(n0 + w * 32 + srow) * 512 + schunk * 8;
  const u16* Bg1 = Bg0 + (size_t)16 * 512;
  int off0 = (w * 32) * 32;
  int off1 = (w * 32 + 16) * 32;

  f32_4 acc[4][4] = {};
  int ach = (lk ^ ((fr >> 2) & 3)) * 8;          // frag chunk (elements) after swizzle

  // prologue: stage k-tile 0 into buffer 0
  async_cp16(Ag0, &As[off0]);
  async_cp16(Ag1, &As[off1]);
  async_cp16(Bg0, &Bs[off0]);
  async_cp16(Bg1, &Bs[off1]);

  for (int it = 0; it < 16; it++) {
    int p = it & 1;
    const u16* Ab = &As[p * 4096];
    const u16* Bb = &Bs[p * 4096];
    __syncthreads();                 // drains vmcnt: buffer p is ready
    if (it < 15) {                   // prefetch next tile into the other buffer
      int kn = (it + 1) * 32;
      int pn = (p ^ 1) * 4096;
      async_cp16(Ag0 + kn, &As[pn + off0]);
      async_cp16(Ag1 + kn, &As[pn + off1]);
      async_cp16(Bg0 + kn, &Bs[pn + off0]);
      async_cp16(Bg1 + kn, &Bs[pn + off1]);
    }
    bf16_8 afr[4], bfr[4];
#pragma unroll
    for (int i = 0; i < 4; i++) {
      afr[i] = *(const bf16_8*)&Ab[(wm + i * 16 + fr) * 32 + ach];
      bfr[i] = *(const bf16_8*)&Bb[(wn + i * 16 + fr) * 32 + ach];
    }
#pragma unroll
    for (int i = 0; i < 4; i++)
#pragma unroll
      for (int j = 0; j < 4; j++)
        acc[i][j] = __builtin_amdgcn_mfma_f32_16x16x32_bf16(afr[i], bfr[j], acc[i][j], 0, 0, 0);
  }

  int rbase = lk * 4;
#pragma unroll
  for (int j = 0; j < 4; j++) {
    int col = n0 + wn + j * 16 + fr;
    float bv = bias[col];
    float csum = 0.f, csq = 0.f;
#pragma unroll
    for (int i = 0; i < 4; i++) {
      int row = m0 + wm + i * 16 + rbase;
#pragma unroll
      for (int r = 0; r < 4; r++) {
        float c = acc[i][j][r] + bv;
        if (mode == 1) c = fmaxf(c, 0.f);
        if (mode == 2) {
          size_t idx = (size_t)(row + r) * 512 + col;
          c += bf2f(resid[idx]);
          outf[idx] = c;
          csum += c; csq = fmaf(c, c, csq);
        } else if (mode == 3) {
          int rr = row + r;    // global M-row = b*256+s ; col = h*64+dh
          size_t idx = ((size_t)((rr >> 8) * 8 + (col >> 6)) * 256 + (rr & 255)) * 64 + (col & 63);
          outb[idx] = f2bf(c);
        } else {
          outb[(size_t)(row + r) * 512 + col] = f2bf(c);
        }
      }
    }
    if (mode == 2) {
      csum += __shfl_xor(csum, 16); csum += __shfl_xor(csum, 32);
      csq  += __shfl_xor(csq, 16);  csq  += __shfl_xor(csq, 32);
      if (lk == 0) {
        atomicAdd(&stats[col], csum);
        atomicAdd(&stats[512 + col], csq);
      }
    }
  }
}

// ---------------- MFMA attention ----------------
// q/k/v head-blocked [b,h,s,dh]. Grid 1024 = (b,h). K staged in LDS (swizzled),
// V transposed in LDS; 4 waves x 4 q-tile iterations, barrier-free after staging.
// Pm is half-width (128 keys) per wave to keep LDS at 80 KB -> 2 blocks/CU.
__global__ __launch_bounds__(256) void k_attn(
    const u16* __restrict__ q, const u16* __restrict__ k,
    const u16* __restrict__ v, u16* __restrict__ attn)
{
  __shared__ u16 Ks[256 * 64];        // 32 KB  row=key (128B), chunk c stores global c^(row&7)
  __shared__ u16 Vt[64 * 256];        // 32 KB  row=d (512B), chunk ck stores global ck^(row&31)
  __shared__ u16 Pm[4][16 * 128];     // 16 KB  per-wave P half, chunk c stores c^(row&7)
  int tid = threadIdx.x;
  int h = blockIdx.x & 7, b = blockIdx.x >> 3;
  size_t hb = (size_t)(b * 8 + h) * (256 * 64);
  int w = tid >> 6, lane = tid & 63;

  // ---- stage K via async cp16, swizzled on the global-address side ----
#pragma unroll
  for (int it = 0; it < 8; it++) {
    int row = it * 32 + w * 8 + (lane >> 3);
    int c = lane & 7;
    const u16* src = k + hb + (size_t)row * 64 + ((c ^ (row & 7)) * 8);
    async_cp16(src, &Ks[(it * 32 + w * 8) * 64]);
  }

  // ---- stage V transposed: Vt[d][key], keys packed pairwise as u32 ----
  {
    int kp = tid & 127;          // key pair index (keys 2kp, 2kp+1)
    int o  = tid >> 7;           // d half (0: d 0..31, 1: d 32..63)
    const u16* vp = v + hb + (size_t)(2 * kp) * 64 + o * 32;
    union { uint4 u[4]; u16 s[32]; } r0, r1;
#pragma unroll
    for (int i = 0; i < 4; i++) {
      r0.u[i] = *(const uint4*)(vp + i * 8);
      r1.u[i] = *(const uint4*)(vp + 64 + i * 8);
    }
#pragma unroll
    for (int d = 0; d < 32; d++) {
      int da = o * 32 + d;
      u32 val = (u32)r0.s[d] | ((u32)r1.s[d] << 16);
      int idx = da * 256 + ((((kp >> 2) ^ (da & 31)) << 3)) + ((2 * kp) & 7);
      *(u32*)&Vt[idx] = val;
    }
  }
  __syncthreads();   // drains cp16 vmcnt + Vt ds_writes

  int fr = lane & 15;          // fragment row/col
  int lk = lane >> 4;          // k-group
  int rbase = lk * 4;

#pragma unroll 1
  for (int qt = 0; qt < 4; qt++) {
    int q0 = qt * 64 + w * 16;   // sequence-local q-row base of this wave

    // ---- QK^T: S[16 x 256] per wave; K frags from LDS ----
    f32_4 accS[16];
    const u16* qbase = q + hb + (size_t)(q0 + fr) * 64 + lk * 8;
    bf16_8 af0 = *(const bf16_8*)(qbase);
    bf16_8 af1 = *(const bf16_8*)(qbase + 32);
#pragma unroll
    for (int j = 0; j < 16; j++) {
      int rx = j * 16 + fr;
      bf16_8 bf0 = *(const bf16_8*)&Ks[rx * 64 + ((lk ^ (fr & 7)) << 3)];
      bf16_8 bf1 = *(const bf16_8*)&Ks[rx * 64 + (((lk + 4) ^ (fr & 7)) << 3)];
      f32_4 z = {};
      z = __builtin_amdgcn_mfma_f32_16x16x32_bf16(af0, bf0, z, 0, 0, 0);
      accS[j] = __builtin_amdgcn_mfma_f32_16x16x32_bf16(af1, bf1, z, 0, 0, 0);
    }

    // ---- softmax over keys ----
    float l[4];
#pragma unroll
    for (int r = 0; r < 4; r++) {
      float m = accS[0][r];
#pragma unroll
      for (int j = 1; j < 16; j++) m = fmaxf(m, accS[j][r]);
      m = fmaxf(m, __shfl_xor(m, 1));
      m = fmaxf(m, __shfl_xor(m, 2));
      m = fmaxf(m, __shfl_xor(m, 4));
      m = fmaxf(m, __shfl_xor(m, 8));
      float s = 0.f;
#pragma unroll
      for (int j = 0; j < 16; j++) {
        float p = __expf((accS[j][r] - m) * 0.125f);   // 1/sqrt(64)
        accS[j][r] = p;
        s += p;
      }
      s += __shfl_xor(s, 1);
      s += __shfl_xor(s, 2);
      s += __shfl_xor(s, 4);
      s += __shfl_xor(s, 8);
      l[r] = s;
    }

    // ---- PV in two key-halves through half-width Pm (wave-private, no barrier) ----
    f32_4 accO[4] = {};
#pragma unroll
    for (int hs = 0; hs < 2; hs++) {
      // write P half (C-layout -> swizzled LDS), own rows only
#pragma unroll
      for (int j8 = 0; j8 < 8; j8++) {
        int col = j8 * 16 + fr;       // 0..127 within half
        int ch = col >> 3, cl = col & 7;
#pragma unroll
        for (int r = 0; r < 4; r++) {
          int row = rbase + r;        // 0..15 within wave region
          Pm[w][row * 128 + ((ch ^ (row & 7)) << 3) + cl] = f2bf(accS[hs * 8 + j8][r]);
        }
      }
      // PV over this half's 128 keys
#pragma unroll
      for (int kk = 0; kk < 4; kk++) {
        bf16_8 pa = *(const bf16_8*)&Pm[w][fr * 128 + (((kk * 4 + lk) ^ (fr & 7)) << 3)];
#pragma unroll
        for (int jd = 0; jd < 4; jd++) {
          int brow = jd * 16 + fr;
          int ck = hs * 16 + kk * 4 + lk;
          bf16_8 vb = *(const bf16_8*)&Vt[brow * 256 + ((ck ^ (brow & 31)) << 3)];
          accO[jd] = __builtin_amdgcn_mfma_f32_16x16x32_bf16(pa, vb, accO[jd], 0, 0, 0);
        }
      }
    }

    // ---- epilogue: normalize by l, store bf16 to [M,512] ----
    float linv[4];
#pragma unroll
    for (int r = 0; r < 4; r++) linv[r] = 1.f / l[r];
    size_t orow0 = (size_t)(b * S_ + q0 + rbase);
#pragma unroll
    for (int jd = 0; jd < 4; jd++) {
      int col = h * DH_ + jd * 16 + fr;
#pragma unroll
      for (int r = 0; r < 4; r++)
        attn[(orow0 + r) * D_ + col] = f2bf(accO[jd][r] * linv[r]);
    }
  }
}

// ---------------- batchnorm ----------------
__global__ __launch_bounds__(256) void k_zero(float* p, int n) {
  int t = blockIdx.x * 256 + threadIdx.x;
  if (t < n) p[t] = 0.f;
}

// 8 elems/thread; writes bf16 (outb) when outf==nullptr, else f32 (final layer)
__global__ __launch_bounds__(256) void k_bnapply(const float* __restrict__ P,
    const float* __restrict__ stats, const float* __restrict__ gamma,
    const float* __restrict__ beta, u16* __restrict__ outb, float* __restrict__ outf)
{
  size_t t8 = ((size_t)blockIdx.x * 256 + threadIdx.x) * 8;
  int f = (int)(t8 & 511);
  const float inv = 1.f / 32768.f;
  float sc[8], sh[8];
#pragma unroll
  for (int i = 0; i < 8; i++) {
    float mu = stats[f + i] * inv;
    float var = stats[512 + f + i] * inv - mu * mu;
    sc[i] = gamma[f + i] * rsqrtf(var + EPS_);
    sh[i] = beta[f + i] - mu * sc[i];
  }
  float4 p0 = *(const float4*)&P[t8];
  float4 p1 = *(const float4*)&P[t8 + 4];
  float o[8] = {p0.x * sc[0] + sh[0], p0.y * sc[1] + sh[1],
                p0.z * sc[2] + sh[2], p0.w * sc[3] + sh[3],
                p1.x * sc[4] + sh[4], p1.y * sc[5] + sh[5],
                p1.z * sc[6] + sh[6], p1.w * sc[7] + sh[7]};
  if (outf) {
    *(float4*)&outf[t8]     = make_float4(o[0], o[1], o[2], o[3]);
    *(float4*)&outf[t8 + 4] = make_float4(o[4], o[5], o[6], o[7]);
  } else {
    u32 u[4];
#pragma unroll
    for (int i = 0; i < 4; i++)
      u[i] = (u32)f2bf(o[2 * i]) | ((u32)f2bf(o[2 * i + 1]) << 16);
    *(uint4*)&outb[t8] = make_uint4(u[0], u[1], u[2], u[3]);
  }
}

// ---------------- launch ----------------
extern "C" void kernel_launch(void* const* d_in, const int* in_sizes, int n_in,
                              void* d_out, int out_size, void* d_ws, size_t ws_size,
                              hipStream_t stream)
{
  const int*   seq = (const int*)d_in[0];
  const float* pos = (const float*)d_in[1];
  const float* emb = (const float*)d_in[2];
  const float* Wq  = (const float*)d_in[3];
  const float* bq  = (const float*)d_in[4];
  const float* Wk  = (const float*)d_in[5];
  const float* bk  = (const float*)d_in[6];
  const float* Wv  = (const float*)d_in[7];
  const float* bv  = (const float*)d_in[8];
  const float* Wo  = (const float*)d_in[9];
  const float* bo  = (const float*)d_in[10];
  const float* g1  = (const float*)d_in[11];
  const float* be1 = (const float*)d_in[12];
  const float* W1  = (const float*)d_in[13];
  const float* b1  = (const float*)d_in[14];
  const float* W2  = (const float*)d_in[15];
  const float* b2  = (const float*)d_in[16];
  const float* g2  = (const float*)d_in[17];
  const float* be2 = (const float*)d_in[18];

  char* ws = (char*)d_ws;
  const size_t SZH = (size_t)M_ * D_ * 2;        // 32 MiB per bf16 activation
  u16* hb16 = (u16*)(ws);                        // master activation (bf16)
  u16* qB   = (u16*)(ws + SZH);
  u16* kB   = (u16*)(ws + 2 * SZH);
  u16* vB   = (u16*)(ws + 3 * SZH);
  u16* aB   = (u16*)(ws + 4 * SZH);
  float* PB = (float*)(ws + 2 * SZH);            // f32 pre-BN, overlays kB,vB (dead then)
  u16* tB   = qB;                                // FFN hidden reuses q
  u16* Wt   = (u16*)(ws + 5 * SZH);
  float* stats = (float*)(ws + 5 * SZH + (size_t)24 * D_ * D_ * 2);

  dim3 blk(256);
  k_zero<<<32, blk, 0, stream>>>(stats, 8192);
  k_transpose<<<dim3(16, 16, 24), blk, 0, stream>>>(Wq, Wk, Wv, Wo, W1, W2, Wt);
  k_embed<<<M_ * 64 / 256, blk, 0, stream>>>(seq, pos, emb, hb16);

  dim3 ggrid(M_ / 128, 512 / 128);
  for (int l = 0; l < L_; l++) {
    const u16* wtq = Wt + (size_t)(l * 6 + 0) * D_ * D_;
    const u16* wtk = Wt + (size_t)(l * 6 + 1) * D_ * D_;
    const u16* wtv = Wt + (size_t)(l * 6 + 2) * D_ * D_;
    const u16* wto = Wt + (size_t)(l * 6 + 3) * D_ * D_;
    const u16* wt1 = Wt + (size_t)(l * 6 + 4) * D_ * D_;
    const u16* wt2 = Wt + (size_t)(l * 6 + 5) * D_ * D_;
    float* st = stats + l * 2048;

    k_gemm<<<ggrid, blk, 0, stream>>>(hb16, wtq, bq + l * D_, nullptr, qB, nullptr, nullptr, 3);
    k_gemm<<<ggrid, blk, 0, stream>>>(hb16, wtk, bk + l * D_, nullptr, kB, nullptr, nullptr, 3);
    k_gemm<<<ggrid, blk, 0, stream>>>(hb16, wtv, bv + l * D_, nullptr, vB, nullptr, nullptr, 3);
    k_attn<<<B_ * H_, blk, 0, stream>>>(qB, kB, vB, aB);
    k_gemm<<<ggrid, blk, 0, stream>>>(aB, wto, bo + l * D_, hb16, nullptr, PB, st, 2);
    k_bnapply<<<8192, blk, 0, stream>>>(PB, st, g1 + l * D_, be1 + l * D_, hb16, nullptr);
    k_gemm<<<ggrid, blk, 0, stream>>>(hb16, wt1, b1 + l * FF_, nullptr, tB, nullptr, nullptr, 1);
    k_gemm<<<ggrid, blk, 0, stream>>>(tB, wt2, b2 + l * D_, hb16, nullptr, PB, st + 1024, 2);
    if (l == L_ - 1)
      k_bnapply<<<8192, blk, 0, stream>>>(PB, st + 1024, g2 + l * D_, be2 + l * D_, nullptr, (float*)d_out);
    else
      k_bnapply<<<8192, blk, 0, stream>>>(PB, st + 1024, g2 + l * D_, be2 + l * D_, hb16, nullptr);
  }
}